// Round 13
// baseline (2490.846 us; speedup 1.0000x reference)
//
#include <hip/hip_runtime.h>

#define BATCH 1024
#define DPAD 10833
#define MROWS 3072
#define NOUT 96
#define XPITCH 100
#define APITCH 84
#define BPITCH 84

// out layout (floats): sh_e1 0, sh_md 10240, sh_e2 20480; pose_e1 30720,
// pose_md 79872, pose_e2 129024; cam_e1 178176, cam_md 181248, cam_e2 184320.

__device__ __forceinline__ unsigned jof(unsigned dg) {   // dg/515
  return (unsigned)(((unsigned long long)dg * 8339743ull) >> 32);
}

// ---------- pool + shape/cam (passed R1-R12) ----------
__global__ __launch_bounds__(256) void pool_shapecam(
    const float* __restrict__ fb, const float* __restrict__ shape_w,
    const float* __restrict__ shape_b, const float* __restrict__ cam_w,
    const float* __restrict__ cam_b, float* __restrict__ out) {
  __shared__ float pooled[2048];
  int b = blockIdx.x;
  const float* base = fb + (size_t)b * 2048 * 64;
  int t = threadIdx.x;
  int sub = t & 15, rgrp = t >> 4;
  for (int it = 0; it < 128; ++it) {
    int rid = it * 16 + rgrp;
    float4 v = *(const float4*)(base + rid * 64 + sub * 4);
    float s = (v.x + v.y) + (v.z + v.w);
    s += __shfl_xor(s, 1); s += __shfl_xor(s, 2);
    s += __shfl_xor(s, 4); s += __shfl_xor(s, 8);
    if (sub == 0) pooled[rid] = s * (1.f / 64.f);
  }
  __syncthreads();
  int wv = t >> 6, ln = t & 63;
  for (int o = wv; o < 39; o += 4) {
    const float* wrow; float bias;
    if (o < 30) { wrow = shape_w + o * 2048; bias = shape_b[o]; }
    else        { wrow = cam_w + (o - 30) * 2048; bias = cam_b[o - 30]; }
    float acc = 0.f;
    #pragma unroll 8
    for (int i = ln; i < 2048; i += 64) acc += pooled[i] * wrow[i];
    acc += __shfl_xor(acc, 1);  acc += __shfl_xor(acc, 2);
    acc += __shfl_xor(acc, 4);  acc += __shfl_xor(acc, 8);
    acc += __shfl_xor(acc, 16); acc += __shfl_xor(acc, 32);
    if (ln == 0) {
      float r = acc + bias;
      if (o < 30) { int g = o / 10, j = o - g * 10; out[g * 10240 + b * 10 + j] = r; }
      else { int oc = o - 30; int g = oc / 3, j = oc - g * 3;
             out[178176 + g * 3072 + b * 3 + j] = r; }
    }
  }
}

// ---------- e1: OpenBLAS kc=384 variant B (passed out3 R10-R12) ----------
__global__ __launch_bounds__(256) void gemm_e1_blasB(
    const float* __restrict__ fj, const float* __restrict__ ji,
    const float* __restrict__ reg_w, float* __restrict__ partA) {
  __shared__ float smem[64 * XPITCH];
  int bi = blockIdx.x;             // 0..63
  int jblk = bi & 3, mg = bi >> 2; // 16 groups x 64 rows
  int tid = threadIdx.x;
  int lane = tid & 63;
  int wv = __builtin_amdgcn_readfirstlane(tid >> 6);
  int o0 = jblk * 24 + wv * 6;
  const float* w0 = reg_w + (size_t)(o0 + 0) * DPAD;
  const float* w1 = reg_w + (size_t)(o0 + 1) * DPAD;
  const float* w2 = reg_w + (size_t)(o0 + 2) * DPAD;
  const float* w3 = reg_w + (size_t)(o0 + 3) * DPAD;
  const float* w4 = reg_w + (size_t)(o0 + 4) * DPAD;
  const float* w5 = reg_w + (size_t)(o0 + 5) * DPAD;

  float acc0 = 0.f, acc1 = 0.f, acc2 = 0.f, acc3 = 0.f, acc4 = 0.f, acc5 = 0.f;
  float res0 = 0.f, res1 = 0.f, res2 = 0.f, res3 = 0.f, res4 = 0.f, res5 = 0.f;
  float4 pre[6];

  auto stage_load = [&](int ch) {
    int d0 = ch * 96;
    #pragma unroll
    for (int i = 0; i < 6; ++i) {
      int q = tid + 256 * i;
      int row = q / 24, c4 = q - row * 24;
      int dg = d0 + c4 * 4;
      unsigned j = jof((unsigned)dg);
      int c = dg - (int)j * 515;
      int b = mg * 64 + row;
      float4 v;
      if (c <= 508) {
        v = *(const float4*)(fj + (size_t)b * 10752 + j * 512 + c);
      } else {
        float tmp[4];
        #pragma unroll
        for (int e = 0; e < 4; ++e) {
          int dge = dg + e;
          unsigned je = jof((unsigned)dge);
          int ce = dge - (int)je * 515;
          tmp[e] = (ce < 512) ? fj[(size_t)b * 10752 + je * 512 + ce]
                              : ji[b * 63 + je * 3 + (ce - 512)];
        }
        v = make_float4(tmp[0], tmp[1], tmp[2], tmp[3]);
      }
      pre[i] = v;
    }
  };

  stage_load(0);
  for (int ch = 0; ch < 112; ++ch) {
    __syncthreads();
    #pragma unroll
    for (int i = 0; i < 6; ++i) {
      int q = tid + 256 * i;
      int row = q / 24, c4 = q - row * 24;
      *(float4*)&smem[row * XPITCH + c4 * 4] = pre[i];
    }
    __syncthreads();
    if (ch + 1 < 112) stage_load(ch + 1);

    int d0 = ch * 96;
    if (ch > 0 && ch <= 108 && (ch & 3) == 0) {
      res0 += acc0; acc0 = 0.f; res1 += acc1; acc1 = 0.f;
      res2 += acc2; acc2 = 0.f; res3 += acc3; acc3 = 0.f;
      res4 += acc4; acc4 = 0.f; res5 += acc5; acc5 = 0.f;
    }
    const float* xrow = &smem[lane * XPITCH];
    if (ch != 110) {
      #pragma unroll 12
      for (int kk = 0; kk < 96; kk += 4) {
        float4 xq = *(const float4*)(xrow + kk);
        float4 q;
        q = *(const float4*)(w0 + d0 + kk);
        acc0 = __builtin_fmaf(xq.x, q.x, acc0); acc0 = __builtin_fmaf(xq.y, q.y, acc0);
        acc0 = __builtin_fmaf(xq.z, q.z, acc0); acc0 = __builtin_fmaf(xq.w, q.w, acc0);
        q = *(const float4*)(w1 + d0 + kk);
        acc1 = __builtin_fmaf(xq.x, q.x, acc1); acc1 = __builtin_fmaf(xq.y, q.y, acc1);
        acc1 = __builtin_fmaf(xq.z, q.z, acc1); acc1 = __builtin_fmaf(xq.w, q.w, acc1);
        q = *(const float4*)(w2 + d0 + kk);
        acc2 = __builtin_fmaf(xq.x, q.x, acc2); acc2 = __builtin_fmaf(xq.y, q.y, acc2);
        acc2 = __builtin_fmaf(xq.z, q.z, acc2); acc2 = __builtin_fmaf(xq.w, q.w, acc2);
        q = *(const float4*)(w3 + d0 + kk);
        acc3 = __builtin_fmaf(xq.x, q.x, acc3); acc3 = __builtin_fmaf(xq.y, q.y, acc3);
        acc3 = __builtin_fmaf(xq.z, q.z, acc3); acc3 = __builtin_fmaf(xq.w, q.w, acc3);
        q = *(const float4*)(w4 + d0 + kk);
        acc4 = __builtin_fmaf(xq.x, q.x, acc4); acc4 = __builtin_fmaf(xq.y, q.y, acc4);
        acc4 = __builtin_fmaf(xq.z, q.z, acc4); acc4 = __builtin_fmaf(xq.w, q.w, acc4);
        q = *(const float4*)(w5 + d0 + kk);
        acc5 = __builtin_fmaf(xq.x, q.x, acc5); acc5 = __builtin_fmaf(xq.y, q.y, acc5);
        acc5 = __builtin_fmaf(xq.z, q.z, acc5); acc5 = __builtin_fmaf(xq.w, q.w, acc5);
      }
    } else {   // last-panel restart at d=10608 (kk=48)
      for (int kk = 0; kk < 48; ++kk) {
        float xv = xrow[kk];
        acc0 = __builtin_fmaf(xv, w0[d0 + kk], acc0);
        acc1 = __builtin_fmaf(xv, w1[d0 + kk], acc1);
        acc2 = __builtin_fmaf(xv, w2[d0 + kk], acc2);
        acc3 = __builtin_fmaf(xv, w3[d0 + kk], acc3);
        acc4 = __builtin_fmaf(xv, w4[d0 + kk], acc4);
        acc5 = __builtin_fmaf(xv, w5[d0 + kk], acc5);
      }
      res0 += acc0; acc0 = 0.f; res1 += acc1; acc1 = 0.f;
      res2 += acc2; acc2 = 0.f; res3 += acc3; acc3 = 0.f;
      res4 += acc4; acc4 = 0.f; res5 += acc5; acc5 = 0.f;
      for (int kk = 48; kk < 96; ++kk) {
        float xv = xrow[kk];
        acc0 = __builtin_fmaf(xv, w0[d0 + kk], acc0);
        acc1 = __builtin_fmaf(xv, w1[d0 + kk], acc1);
        acc2 = __builtin_fmaf(xv, w2[d0 + kk], acc2);
        acc3 = __builtin_fmaf(xv, w3[d0 + kk], acc3);
        acc4 = __builtin_fmaf(xv, w4[d0 + kk], acc4);
        acc5 = __builtin_fmaf(xv, w5[d0 + kk], acc5);
      }
    }
  }
  int grow = mg * 64 + lane;
  float* pp = partA + ((size_t)grow * NOUT + o0) * 2;
  pp[0] = res0; pp[1] = acc0; pp[2] = res1; pp[3] = acc1;
  pp[4] = res2; pp[5] = acc2; pp[6] = res3; pp[7] = acc3;
  pp[8] = res4; pp[9] = acc4; pp[10] = res5; pp[11] = acc5;
}

// ---------- md: unbuffered c_einsum npyv-SSE3, d<10800, 4 lanes ----------
__global__ __launch_bounds__(256) void gemm_md_sse3(
    const float* __restrict__ fj, const float* __restrict__ ji,
    const float* __restrict__ reg_w, float* __restrict__ partB) {
  #pragma clang fp contract(off)
  __shared__ float As[16 * APITCH];
  __shared__ float Bs[96 * BPITCH];
  int blk = blockIdx.x;            // 0..63, 16 rows each
  int t = threadIdx.x;
  int tm = t >> 4, tn = t & 15;
  int m0 = blk * 16;

  float acc[6][4];
  #pragma unroll
  for (int c = 0; c < 6; ++c)
    #pragma unroll
    for (int l = 0; l < 4; ++l) acc[c][l] = 0.f;

  const float4* As4 = (const float4*)As;
  const float4* Bs4 = (const float4*)Bs;

  for (int r = 0; r < 135; ++r) {  // 135*80 = 10800
    int d0 = r * 80;
    #pragma unroll
    for (int i = 0; i < 5; ++i) {
      int idx = t + 256 * i;
      int mm = idx / 80, dd = idx - mm * 80;
      int dg = d0 + dd;
      unsigned j = jof((unsigned)dg);
      int c = dg - (int)j * 515;
      int b = m0 + mm;
      As[mm * APITCH + dd] = (c < 512) ? fj[(size_t)b * 10752 + j * 512 + c]
                                       : ji[b * 63 + j * 3 + (c - 512)];
    }
    #pragma unroll
    for (int i = 0; i < 30; ++i) {
      int idx = t + 256 * i;
      int o = idx / 80, dd = idx - o * 80;
      Bs[o * BPITCH + dd] = reg_w[(size_t)o * DPAD + d0 + dd];
    }
    __syncthreads();
    #pragma unroll
    for (int bb = 0; bb < 5; ++bb) {
      float4 qa0 = As4[tm * (APITCH / 4) + bb * 4 + 0];
      float4 qa1 = As4[tm * (APITCH / 4) + bb * 4 + 1];
      float4 qa2 = As4[tm * (APITCH / 4) + bb * 4 + 2];
      float4 qa3 = As4[tm * (APITCH / 4) + bb * 4 + 3];
      float a[16] = {qa0.x, qa0.y, qa0.z, qa0.w, qa1.x, qa1.y, qa1.z, qa1.w,
                     qa2.x, qa2.y, qa2.z, qa2.w, qa3.x, qa3.y, qa3.z, qa3.w};
      #pragma unroll
      for (int c = 0; c < 6; ++c) {
        int o = tn + 16 * c;
        float4 qb0 = Bs4[o * (BPITCH / 4) + bb * 4 + 0];
        float4 qb1 = Bs4[o * (BPITCH / 4) + bb * 4 + 1];
        float4 qb2 = Bs4[o * (BPITCH / 4) + bb * 4 + 2];
        float4 qb3 = Bs4[o * (BPITCH / 4) + bb * 4 + 3];
        float bv[16] = {qb0.x, qb0.y, qb0.z, qb0.w, qb1.x, qb1.y, qb1.z, qb1.w,
                        qb2.x, qb2.y, qb2.z, qb2.w, qb3.x, qb3.y, qb3.z, qb3.w};
        #pragma unroll
        for (int l = 0; l < 4; ++l) {
          float v = acc[c][l];
          float t3 = a[12 + l] * bv[12 + l]; v = v + t3;   // descending sub-vectors
          float t2 = a[8 + l]  * bv[8 + l];  v = v + t2;
          float t1 = a[4 + l]  * bv[4 + l];  v = v + t1;
          float t0 = a[l]      * bv[l];      v = v + t0;
          acc[c][l] = v;
        }
      }
    }
    __syncthreads();
  }
  int m = m0 + tm;
  #pragma unroll
  for (int c = 0; c < 6; ++c) {
    int o = tn + 16 * c;
    float4 st = make_float4(acc[c][0], acc[c][1], acc[c][2], acc[c][3]);
    *(float4*)(partB + ((size_t)m * NOUT + o) * 4) = st;
  }
}

// ---------- e2: unbuffered c_einsum npyv-AVX2+FMA, d<10752, 8 lanes ----------
// Per 32-block (blocks ascending): lane l: v = fma(a[l],b[l], fma(a[8+l],b[8+l],
// fma(a[16+l],b[16+l], fma(a[24+l],b[24+l], v))))  (ab3 applied first).
__global__ __launch_bounds__(256) void gemm_e2_avx2(
    const float* __restrict__ fj, const float* __restrict__ ji,
    const float* __restrict__ reg_w, float* __restrict__ partC) {
  #pragma clang fp contract(off)
  __shared__ float As[16 * 68];
  __shared__ float Bs[96 * 68];
  int blk = blockIdx.x;            // 0..63, 16 rows each
  int t = threadIdx.x;
  int tm = t >> 4, tn = t & 15;
  int m0 = blk * 16;

  float acc[6][8];
  #pragma unroll
  for (int c = 0; c < 6; ++c)
    #pragma unroll
    for (int l = 0; l < 8; ++l) acc[c][l] = 0.f;

  for (int r = 0; r < 168; ++r) {            // 168*64 = 10752 = 336 32-blocks
    int d0 = r * 64;
    #pragma unroll
    for (int i = 0; i < 4; ++i) {
      int idx = t + 256 * i;
      int mm = idx >> 6, dd = idx & 63;
      int dg = d0 + dd;
      unsigned j = jof((unsigned)dg);
      int c = dg - (int)j * 515;
      int b = m0 + mm;
      As[mm * 68 + dd] = (c < 512) ? fj[(size_t)b * 10752 + j * 512 + c]
                                   : ji[b * 63 + j * 3 + (c - 512)];
    }
    #pragma unroll
    for (int i = 0; i < 24; ++i) {
      int idx = t + 256 * i;
      int o = idx >> 6, dd = idx & 63;
      Bs[o * 68 + dd] = reg_w[(size_t)o * DPAD + d0 + dd];
    }
    __syncthreads();
    #pragma unroll
    for (int bb = 0; bb < 2; ++bb) {         // two 32-blocks per round
      const float* arow = &As[tm * 68 + bb * 32];
      float a[32];
      #pragma unroll
      for (int q = 0; q < 8; ++q) {
        float4 qa = *(const float4*)(arow + q * 4);
        a[q * 4 + 0] = qa.x; a[q * 4 + 1] = qa.y;
        a[q * 4 + 2] = qa.z; a[q * 4 + 3] = qa.w;
      }
      #pragma unroll
      for (int c = 0; c < 6; ++c) {
        int o = tn + 16 * c;
        const float* brow = &Bs[o * 68 + bb * 32];
        float bv[32];
        #pragma unroll
        for (int q = 0; q < 8; ++q) {
          float4 qb = *(const float4*)(brow + q * 4);
          bv[q * 4 + 0] = qb.x; bv[q * 4 + 1] = qb.y;
          bv[q * 4 + 2] = qb.z; bv[q * 4 + 3] = qb.w;
        }
        #pragma unroll
        for (int l = 0; l < 8; ++l) {
          float v = acc[c][l];
          v = __builtin_fmaf(a[24 + l], bv[24 + l], v);   // ab3 first
          v = __builtin_fmaf(a[16 + l], bv[16 + l], v);
          v = __builtin_fmaf(a[8 + l],  bv[8 + l],  v);
          v = __builtin_fmaf(a[l],      bv[l],      v);
          acc[c][l] = v;
        }
      }
    }
    __syncthreads();
  }
  int m = m0 + tm;
  #pragma unroll
  for (int c = 0; c < 6; ++c) {
    int o = tn + 16 * c;
    float* p = partC + ((size_t)m * NOUT + o) * 8;
    *(float4*)(p)     = make_float4(acc[c][0], acc[c][1], acc[c][2], acc[c][3]);
    *(float4*)(p + 4) = make_float4(acc[c][4], acc[c][5], acc[c][6], acc[c][7]);
  }
}

// ---------- glibc (fdlibm) acosf port (validated R10-R12) ----------
__device__ __forceinline__ float acosf_glibc(float x) {
  #pragma clang fp contract(off)
  const float one = 1.0f;
  const float pi = 3.1415925026e+00f;
  const float pio2_hi = 1.5707962513e+00f;
  const float pio2_lo = 7.5497894159e-08f;
  const float pS0 =  1.6666586697e-01f;
  const float pS1 = -4.2743422091e-02f;
  const float pS2 = -8.6563630030e-03f;
  const float qS1 = -7.0662963390e-01f;
  int hx = __float_as_int(x);
  int ix = hx & 0x7fffffff;
  if (ix >= 0x3f800000) {
    if (ix == 0x3f800000) return (hx > 0) ? 0.0f : (pi + 2.0f * pio2_lo);
    return (x - x) / (x - x);
  }
  if (ix < 0x3f000000) {
    if (ix <= 0x32800000) return pio2_hi + pio2_lo;
    float z = x * x;
    float p = z * (pS0 + z * (pS1 + z * pS2));
    float q = one + z * qS1;
    float r = p / q;
    float t1 = x * r;
    float t2 = pio2_lo - t1;
    float t3 = x - t2;
    return pio2_hi - t3;
  } else if (hx < 0) {
    float z = (one + x) * 0.5f;
    float p = z * (pS0 + z * (pS1 + z * pS2));
    float q = one + z * qS1;
    float s = sqrtf(z);
    float r = p / q;
    float w = r * s - pio2_lo;
    float u = s + w;
    return pi - 2.0f * u;
  } else {
    float z = (one - x) * 0.5f;
    float s = sqrtf(z);
    float df = __int_as_float(__float_as_int(s) & 0xfffff000);
    float c = (z - df * df) / (s + df);
    float p = z * (pS0 + z * (pS1 + z * pS2));
    float q = one + z * qS1;
    float r = p / q;
    float w = r * s + c;
    float u = df + w;
    return 2.0f * u;
  }
}

// ---------- f32 rot6d, numpy op-for-op (validated R10-R12) ----------
__device__ __forceinline__ void emit_aa32(const float p[6], float* __restrict__ pout) {
  #pragma clang fp contract(off)
  const float CLO = (float)(-1.0 + 1e-6);
  const float CHI = (float)(1.0 - 1e-6);
  float a1x = p[0], a2x = p[1];
  float a1y = p[2], a2y = p[3];
  float a1z = p[4], a2z = p[5];
  float n1 = sqrtf(((a1x * a1x) + (a1y * a1y)) + (a1z * a1z));
  float n1c = fmaxf(n1, 1e-12f);
  float b1x = a1x / n1c, b1y = a1y / n1c, b1z = a1z / n1c;
  float d12 = ((b1x * a2x) + (b1y * a2y)) + (b1z * a2z);
  float px = a2x - (d12 * b1x);
  float py = a2y - (d12 * b1y);
  float pz = a2z - (d12 * b1z);
  float n2 = sqrtf(((px * px) + (py * py)) + (pz * pz));
  float n2c = fmaxf(n2, 1e-12f);
  float b2x = px / n2c, b2y = py / n2c, b2z = pz / n2c;
  float b3x = (b1y * b2z) - (b1z * b2y);
  float b3y = (b1z * b2x) - (b1x * b2z);
  float b3z = (b1x * b2y) - (b1y * b2x);
  float tr = (b1x + b2y) + b3z;
  float cth = (tr - 1.0f) * 0.5f;
  cth = fminf(fmaxf(cth, CLO), CHI);
  float ang = acosf_glibc(cth);
  float sn = (float)sin((double)ang);
  float sc = ang / (2.0f * sn);
  pout[0] = (b2z - b3y) * sc;
  pout[1] = (b3x - b1z) * sc;
  pout[2] = (b1y - b2x) * sc;
}

// ---------- finish tails per stream + bias + rot6d ----------
__global__ __launch_bounds__(256) void chain_np(
    const float* __restrict__ partA, const float* __restrict__ partB,
    const float* __restrict__ partC,
    const float* __restrict__ fj_e1, const float* __restrict__ fj_md,
    const float* __restrict__ fj_e2, const float* __restrict__ ji_e1,
    const float* __restrict__ ji_md, const float* __restrict__ ji_e2,
    const float* __restrict__ reg_w, const float* __restrict__ reg_b,
    float* __restrict__ out) {
  #pragma clang fp contract(off)
  int t = blockIdx.x * 256 + threadIdx.x;
  if (t >= MROWS) return;
  int s = t >> 10, b = t & 1023;
  const float* fjs = (s == 0) ? fj_e1 : (s == 1) ? fj_md : fj_e2;
  const float* jis = (s == 0) ? ji_e1 : (s == 1) ? ji_md : ji_e2;
  float* pout = out + 30720 + s * (BATCH * 48) + b * 48;

  // xall[k] = x at d = 10744+k; k<71 from inputs, k=71..88 ancestor slots.
  float xall[89];
  #pragma unroll
  for (int k = 0; k < 68; ++k) xall[k] = fjs[(size_t)b * 10752 + 10684 + k];
  #pragma unroll
  for (int k = 0; k < 3; ++k) xall[68 + k] = jis[b * 63 + 60 + k];

  float p0[6], pa[6], pb[6], pc[6];
  float anc[18];

  auto do_joint = [&](int i, int na, float* pz) {
    #pragma unroll
    for (int k = 0; k < 18; ++k) xall[71 + k] = (k < na * 6) ? anc[k] : 0.f;
    #pragma unroll
    for (int oo = 0; oo < 6; ++oo) {
      const float* w = reg_w + (size_t)(i * 6 + oo) * DPAD;
      float total;
      if (s == 0) {
        // BLAS-B: continue live panel ascending FMA d 10752..10832, res+acc
        const float* pp = partA + ((size_t)b * NOUT + i * 6 + oo) * 2;
        float res = pp[0], acc = pp[1];
        #pragma unroll
        for (int k = 8; k < 89; ++k)
          acc = __builtin_fmaf(xall[k], w[10744 + k], acc);
        total = res + acc;
      } else if (s == 1) {
        // SSE3 npyv: blocks 675,676 desc; tillz d=10832 -> lane0; hsum
        const float* pp = partB + ((size_t)b * NOUT + i * 6 + oo) * 4;
        float v[4] = {pp[0], pp[1], pp[2], pp[3]};
        // block 675 (d 10800..10815): xall idx 56..71
        { float q = xall[68] * w[10812]; v[0] = v[0] + q; }
        { float q = xall[69] * w[10813]; v[1] = v[1] + q; }
        { float q = xall[70] * w[10814]; v[2] = v[2] + q; }
        { float q = xall[71] * w[10815]; v[3] = v[3] + q; }
        #pragma unroll
        for (int l = 0; l < 4; ++l) { float q = xall[64 + l] * w[10808 + l]; v[l] = v[l] + q; }
        #pragma unroll
        for (int l = 0; l < 4; ++l) { float q = xall[60 + l] * w[10804 + l]; v[l] = v[l] + q; }
        #pragma unroll
        for (int l = 0; l < 4; ++l) { float q = xall[56 + l] * w[10800 + l]; v[l] = v[l] + q; }
        // block 676 (d 10816..10831): xall idx 72..87
        #pragma unroll
        for (int l = 0; l < 4; ++l) { float q = xall[84 + l] * w[10828 + l]; v[l] = v[l] + q; }
        #pragma unroll
        for (int l = 0; l < 4; ++l) { float q = xall[80 + l] * w[10824 + l]; v[l] = v[l] + q; }
        #pragma unroll
        for (int l = 0; l < 4; ++l) { float q = xall[76 + l] * w[10820 + l]; v[l] = v[l] + q; }
        #pragma unroll
        for (int l = 0; l < 4; ++l) { float q = xall[72 + l] * w[10816 + l]; v[l] = v[l] + q; }
        // tillz tail: d=10832 lands in LANE 0 before hsum
        { float q = xall[88] * w[10832]; v[0] = v[0] + q; }
        total = (v[0] + v[1]) + (v[2] + v[3]);
      } else {
        // AVX2 npyv: blocks 336,337 desc-FMA; 2 vstep + tillz lane0; hsum8
        const float* pp = partC + ((size_t)b * NOUT + i * 6 + oo) * 8;
        float v[8] = {pp[0], pp[1], pp[2], pp[3], pp[4], pp[5], pp[6], pp[7]};
        // block 336 (d 10752..10783): xall base 8
        #pragma unroll
        for (int l = 0; l < 8; ++l) {
          float x = v[l];
          x = __builtin_fmaf(xall[32 + l], w[10776 + l], x);   // ab3
          x = __builtin_fmaf(xall[24 + l], w[10768 + l], x);
          x = __builtin_fmaf(xall[16 + l], w[10760 + l], x);
          x = __builtin_fmaf(xall[8 + l],  w[10752 + l], x);
          v[l] = x;
        }
        // block 337 (d 10784..10815): xall base 40
        #pragma unroll
        for (int l = 0; l < 8; ++l) {
          float x = v[l];
          x = __builtin_fmaf(xall[64 + l], w[10808 + l], x);   // ab3
          x = __builtin_fmaf(xall[56 + l], w[10800 + l], x);
          x = __builtin_fmaf(xall[48 + l], w[10792 + l], x);
          x = __builtin_fmaf(xall[40 + l], w[10784 + l], x);
          v[l] = x;
        }
        // tillz loop: d 10816..10823, 10824..10831, then [10832] lane0
        #pragma unroll
        for (int l = 0; l < 8; ++l) v[l] = __builtin_fmaf(xall[72 + l], w[10816 + l], v[l]);
        #pragma unroll
        for (int l = 0; l < 8; ++l) v[l] = __builtin_fmaf(xall[80 + l], w[10824 + l], v[l]);
        v[0] = __builtin_fmaf(xall[88], w[10832], v[0]);
        total = ((v[0] + v[1]) + (v[2] + v[3])) + ((v[4] + v[5]) + (v[6] + v[7]));
      }
      pz[oo] = total + reg_b[i * 6 + oo];
    }
    emit_aa32(pz, pout + i * 3);
  };

  do_joint(0, 0, p0);
  for (int f = 1; f < 16; f += 3) {
    #pragma unroll
    for (int k = 0; k < 6; ++k) anc[k] = p0[k];
    do_joint(f, 1, pa);
    #pragma unroll
    for (int k = 0; k < 6; ++k) anc[6 + k] = pa[k];
    do_joint(f + 1, 2, pb);
    #pragma unroll
    for (int k = 0; k < 6; ++k) anc[12 + k] = pb[k];
    do_joint(f + 2, 3, pc);
  }
}

extern "C" void kernel_launch(void* const* d_in, const int* in_sizes, int n_in,
                              void* d_out, int out_size, void* d_ws, size_t ws_size,
                              hipStream_t stream) {
  (void)in_sizes; (void)n_in; (void)out_size; (void)ws_size;
  const float* feat_blur = (const float*)d_in[0];
  const float* fj_e1 = (const float*)d_in[1];
  const float* fj_md = (const float*)d_in[2];
  const float* fj_e2 = (const float*)d_in[3];
  const float* ji_e1 = (const float*)d_in[4];
  const float* ji_md = (const float*)d_in[5];
  const float* ji_e2 = (const float*)d_in[6];
  const float* shape_w = (const float*)d_in[7];
  const float* shape_b = (const float*)d_in[8];
  const float* cam_w = (const float*)d_in[9];
  const float* cam_b = (const float*)d_in[10];
  const float* reg_w = (const float*)d_in[11];
  const float* reg_b = (const float*)d_in[12];
  float* out = (float*)d_out;
  float* ws = (float*)d_ws;
  float* partA = ws;                       // e1 BLAS-B   [1024][96][2]
  float* partB = ws + 196608;              // md SSE3     [1024][96][4]
  float* partC = ws + 196608 + 393216;     // e2 AVX2     [1024][96][8]

  hipLaunchKernelGGL(pool_shapecam, dim3(BATCH), dim3(256), 0, stream,
                     feat_blur, shape_w, shape_b, cam_w, cam_b, out);
  hipLaunchKernelGGL(gemm_e1_blasB, dim3(64), dim3(256), 0, stream,
                     fj_e1, ji_e1, reg_w, partA);
  hipLaunchKernelGGL(gemm_md_sse3, dim3(64), dim3(256), 0, stream,
                     fj_md, ji_md, reg_w, partB);
  hipLaunchKernelGGL(gemm_e2_avx2, dim3(64), dim3(256), 0, stream,
                     fj_e2, ji_e2, reg_w, partC);
  hipLaunchKernelGGL(chain_np, dim3((MROWS + 255) / 256), dim3(256), 0, stream,
                     partA, partB, partC, fj_e1, fj_md, fj_e2,
                     ji_e1, ji_md, ji_e2, reg_w, reg_b, out);
}

// Round 15
// 1002.594 us; speedup vs baseline: 2.4844x; 2.4844x over previous
//
#include <hip/hip_runtime.h>

#define BATCH 1024
#define DPAD 10833
#define MROWS 3072
#define NOUT 96
#define XP 100            // xs pitch (floats)
#define WP 96             // ws pitch (wave-uniform broadcast reads)
#define GEMM_BLOCKS 192
#define POOL_BLOCKS 1024

// out layout (floats): sh_e1 0, sh_md 10240, sh_e2 20480; pose_e1 30720,
// pose_md 79872, pose_e2 129024; cam_e1 178176, cam_md 181248, cam_e2 184320.

__device__ __forceinline__ unsigned jof(unsigned dg) {   // dg/515
  return (unsigned)(((unsigned long long)dg * 8339743ull) >> 32);
}

// ---------- fused: [0,64) e1 BLAS-B, [64,128) md SSE3, [128,192) e2 AVX2, rest pool ----------
// Per-stream FP orders frozen to R13's passing combination (absmax 0.0625):
//  e1: OpenBLAS kc=384-B ascending-FMA panels (folds at d mult of 384; restart d=10608)
//  md: SSE3-npyv 16-blocks ascending, DESCENDING sub-vectors, separate mul/add
//  e2: AVX2-npyv 32-blocks ascending, desc-FMA (ab3 first), 8 lanes
// GEMM covers d<10752; chain_np finishes tails exactly as R13.
__global__ __launch_bounds__(256, 2) void fused_all(
    const float* __restrict__ fb, const float* __restrict__ shape_w,
    const float* __restrict__ shape_b, const float* __restrict__ cam_w,
    const float* __restrict__ cam_b,
    const float* __restrict__ fj_e1, const float* __restrict__ fj_md,
    const float* __restrict__ fj_e2, const float* __restrict__ ji_e1,
    const float* __restrict__ ji_md, const float* __restrict__ ji_e2,
    const float* __restrict__ reg_w,
    float* __restrict__ partA, float* __restrict__ partB,
    float* __restrict__ partC, float* __restrict__ out) {
  __shared__ float xs[64 * XP];    // 25.6 KB; pool aliases first 2048 floats
  __shared__ float ws[24 * WP];    // 9.2 KB
  int tid = threadIdx.x;
  int bi = blockIdx.x;

  if (bi < GEMM_BLOCKS) {
    int path = bi >> 6;            // 0=e1, 1=md, 2=e2
    int bj = bi & 63;
    int ob = bj & 3, mg = bj >> 2; // 16 m-groups x 64 rows; 4 o-blocks x 24
    const float* fjs = (path == 0) ? fj_e1 : (path == 1) ? fj_md : fj_e2;
    const float* jis = (path == 0) ? ji_e1 : (path == 1) ? ji_md : ji_e2;
    int lane = tid & 63;
    int wv = tid >> 6;
    int o0 = ob * 24;

    float4 px[6];
    float pw[9];
    auto pre_load = [&](int ch) {
      int d0 = ch * 96;
      #pragma unroll
      for (int i = 0; i < 6; ++i) {          // x: 64 rows x 24 float4
        int idx = tid + 256 * i;
        int row = idx / 24, c4 = idx - row * 24;
        int dg = d0 + c4 * 4;
        unsigned j = jof((unsigned)dg);
        int c = dg - (int)j * 515;
        int b = mg * 64 + row;
        float4 v;
        if (c <= 508) {
          v = *(const float4*)(fjs + (size_t)b * 10752 + j * 512 + c);
        } else {
          float tmp[4];
          #pragma unroll
          for (int e = 0; e < 4; ++e) {
            int dge = dg + e;
            unsigned je = jof((unsigned)dge);
            int ce = dge - (int)je * 515;
            tmp[e] = (ce < 512) ? fjs[(size_t)b * 10752 + je * 512 + ce]
                                : jis[b * 63 + je * 3 + (ce - 512)];
          }
          v = make_float4(tmp[0], tmp[1], tmp[2], tmp[3]);
        }
        px[i] = v;
      }
      #pragma unroll
      for (int i = 0; i < 9; ++i) {          // w: 24 o x 96 d
        int idx = tid + 256 * i;             // < 2304
        int wo = idx / 96, wd = idx - wo * 96;
        pw[i] = reg_w[(size_t)(o0 + wo) * DPAD + d0 + wd];
      }
    };
    auto commit = [&]() {
      #pragma unroll
      for (int i = 0; i < 6; ++i) {
        int idx = tid + 256 * i;
        int row = idx / 24, c4 = idx - row * 24;
        *(float4*)&xs[row * XP + c4 * 4] = px[i];
      }
      #pragma unroll
      for (int i = 0; i < 9; ++i) {
        int idx = tid + 256 * i;
        int wo = idx / 96, wd = idx - wo * 96;
        ws[wo * WP + wd] = pw[i];
      }
    };

    if (path == 0) {
      // ---------------- e1: BLAS-B ascending-FMA panels ----------------
      float res[6], acc[6];
      #pragma unroll
      for (int c = 0; c < 6; ++c) { res[c] = 0.f; acc[c] = 0.f; }
      pre_load(0);
      for (int ch = 0; ch < 112; ++ch) {
        __syncthreads();
        commit();
        __syncthreads();
        if (ch + 1 < 112) pre_load(ch + 1);
        if (ch > 0 && ch <= 108 && (ch & 3) == 0) {   // panel starts 384..10368
          #pragma unroll
          for (int c = 0; c < 6; ++c) { res[c] += acc[c]; acc[c] = 0.f; }
        }
        const float* xrow = &xs[lane * XP];
        if (ch != 110) {
          #pragma unroll 8
          for (int kk = 0; kk < 96; kk += 4) {
            float4 xq = *(const float4*)(xrow + kk);
            #pragma unroll
            for (int c = 0; c < 6; ++c) {
              float4 qb = *(const float4*)(&ws[(wv * 6 + c) * WP + kk]);
              float v = acc[c];
              v = __builtin_fmaf(xq.x, qb.x, v);
              v = __builtin_fmaf(xq.y, qb.y, v);
              v = __builtin_fmaf(xq.z, qb.z, v);
              v = __builtin_fmaf(xq.w, qb.w, v);
              acc[c] = v;
            }
          }
        } else {   // last-panel restart at d=10608 (kk=48 of chunk 110)
          for (int kk = 0; kk < 48; ++kk) {
            float xv = xrow[kk];
            #pragma unroll
            for (int c = 0; c < 6; ++c)
              acc[c] = __builtin_fmaf(xv, ws[(wv * 6 + c) * WP + kk], acc[c]);
          }
          #pragma unroll
          for (int c = 0; c < 6; ++c) { res[c] += acc[c]; acc[c] = 0.f; }
          for (int kk = 48; kk < 96; ++kk) {
            float xv = xrow[kk];
            #pragma unroll
            for (int c = 0; c < 6; ++c)
              acc[c] = __builtin_fmaf(xv, ws[(wv * 6 + c) * WP + kk], acc[c]);
          }
        }
      }
      int m = mg * 64 + lane;
      float* pp = partA + ((size_t)m * NOUT + o0 + wv * 6) * 2;
      #pragma unroll
      for (int c = 0; c < 6; ++c) { pp[c * 2] = res[c]; pp[c * 2 + 1] = acc[c]; }
      return;
    } else if (path == 1) {
      // ---------------- md: SSE3-npyv, 4 lanes, desc subs, mul+add ----------------
      #pragma clang fp contract(off)
      float acc[6][4];
      #pragma unroll
      for (int c = 0; c < 6; ++c)
        #pragma unroll
        for (int l = 0; l < 4; ++l) acc[c][l] = 0.f;
      pre_load(0);
      for (int ch = 0; ch < 112; ++ch) {     // 672 16-blocks
        __syncthreads();
        commit();
        __syncthreads();
        if (ch + 1 < 112) pre_load(ch + 1);
        const float* xrow = &xs[lane * XP];
        #pragma unroll
        for (int bb = 0; bb < 6; ++bb) {
          float4 qa0 = *(const float4*)(xrow + bb * 16 + 0);
          float4 qa1 = *(const float4*)(xrow + bb * 16 + 4);
          float4 qa2 = *(const float4*)(xrow + bb * 16 + 8);
          float4 qa3 = *(const float4*)(xrow + bb * 16 + 12);
          float a[16] = {qa0.x, qa0.y, qa0.z, qa0.w, qa1.x, qa1.y, qa1.z, qa1.w,
                         qa2.x, qa2.y, qa2.z, qa2.w, qa3.x, qa3.y, qa3.z, qa3.w};
          #pragma unroll
          for (int c = 0; c < 6; ++c) {
            const float* wrow = &ws[(wv * 6 + c) * WP + bb * 16];
            float4 qb0 = *(const float4*)(wrow + 0);
            float4 qb1 = *(const float4*)(wrow + 4);
            float4 qb2 = *(const float4*)(wrow + 8);
            float4 qb3 = *(const float4*)(wrow + 12);
            float bv[16] = {qb0.x, qb0.y, qb0.z, qb0.w, qb1.x, qb1.y, qb1.z, qb1.w,
                            qb2.x, qb2.y, qb2.z, qb2.w, qb3.x, qb3.y, qb3.z, qb3.w};
            #pragma unroll
            for (int l = 0; l < 4; ++l) {
              float v = acc[c][l];
              float t3 = a[12 + l] * bv[12 + l]; v = v + t3;   // desc subs
              float t2 = a[8 + l]  * bv[8 + l];  v = v + t2;
              float t1 = a[4 + l]  * bv[4 + l];  v = v + t1;
              float t0 = a[l]      * bv[l];      v = v + t0;
              acc[c][l] = v;
            }
          }
        }
      }
      int m = mg * 64 + lane;
      #pragma unroll
      for (int c = 0; c < 6; ++c)
        *(float4*)(partB + ((size_t)m * NOUT + o0 + wv * 6 + c) * 4) =
            make_float4(acc[c][0], acc[c][1], acc[c][2], acc[c][3]);
      return;
    } else {
      // ---------------- e2: AVX2-npyv, 8 lanes, desc-FMA ----------------
      #pragma clang fp contract(off)
      float acc[6][8];
      #pragma unroll
      for (int c = 0; c < 6; ++c)
        #pragma unroll
        for (int l = 0; l < 8; ++l) acc[c][l] = 0.f;
      pre_load(0);
      for (int ch = 0; ch < 112; ++ch) {     // 336 32-blocks
        __syncthreads();
        commit();
        __syncthreads();
        if (ch + 1 < 112) pre_load(ch + 1);
        const float* xrow = &xs[lane * XP];
        #pragma unroll
        for (int bb = 0; bb < 3; ++bb) {
          float a[32];
          #pragma unroll
          for (int q = 0; q < 8; ++q) {
            float4 qa = *(const float4*)(xrow + bb * 32 + q * 4);
            a[q * 4 + 0] = qa.x; a[q * 4 + 1] = qa.y;
            a[q * 4 + 2] = qa.z; a[q * 4 + 3] = qa.w;
          }
          #pragma unroll
          for (int c = 0; c < 6; ++c) {
            const float* wrow = &ws[(wv * 6 + c) * WP + bb * 32];
            float bv[32];
            #pragma unroll
            for (int q = 0; q < 8; ++q) {
              float4 qb = *(const float4*)(wrow + q * 4);
              bv[q * 4 + 0] = qb.x; bv[q * 4 + 1] = qb.y;
              bv[q * 4 + 2] = qb.z; bv[q * 4 + 3] = qb.w;
            }
            #pragma unroll
            for (int l = 0; l < 8; ++l) {
              float v = acc[c][l];
              v = __builtin_fmaf(a[24 + l], bv[24 + l], v);   // ab3 first
              v = __builtin_fmaf(a[16 + l], bv[16 + l], v);
              v = __builtin_fmaf(a[8 + l],  bv[8 + l],  v);
              v = __builtin_fmaf(a[l],      bv[l],      v);
              acc[c][l] = v;
            }
          }
        }
      }
      int m = mg * 64 + lane;
      #pragma unroll
      for (int c = 0; c < 6; ++c) {
        float* p = partC + ((size_t)m * NOUT + o0 + wv * 6 + c) * 8;
        *(float4*)(p)     = make_float4(acc[c][0], acc[c][1], acc[c][2], acc[c][3]);
        *(float4*)(p + 4) = make_float4(acc[c][4], acc[c][5], acc[c][6], acc[c][7]);
      }
      return;
    }
  }

  // ---------------- pool + shape/cam (passed R1-R13) ----------------
  {
    float* pooled = xs;
    int b = bi - GEMM_BLOCKS;
    const float* base = fb + (size_t)b * 2048 * 64;
    int sub = tid & 15, rgrp = tid >> 4;
    for (int it = 0; it < 128; ++it) {
      int rid = it * 16 + rgrp;
      float4 v = *(const float4*)(base + rid * 64 + sub * 4);
      float s = (v.x + v.y) + (v.z + v.w);
      s += __shfl_xor(s, 1); s += __shfl_xor(s, 2);
      s += __shfl_xor(s, 4); s += __shfl_xor(s, 8);
      if (sub == 0) pooled[rid] = s * (1.f / 64.f);
    }
    __syncthreads();
    int wv = tid >> 6, ln = tid & 63;
    for (int o = wv; o < 39; o += 4) {
      const float* wrow; float bias;
      if (o < 30) { wrow = shape_w + o * 2048; bias = shape_b[o]; }
      else        { wrow = cam_w + (o - 30) * 2048; bias = cam_b[o - 30]; }
      float acc = 0.f;
      #pragma unroll 8
      for (int i = ln; i < 2048; i += 64) acc += pooled[i] * wrow[i];
      acc += __shfl_xor(acc, 1);  acc += __shfl_xor(acc, 2);
      acc += __shfl_xor(acc, 4);  acc += __shfl_xor(acc, 8);
      acc += __shfl_xor(acc, 16); acc += __shfl_xor(acc, 32);
      if (ln == 0) {
        float r = acc + bias;
        if (o < 30) { int g = o / 10, j = o - g * 10; out[g * 10240 + b * 10 + j] = r; }
        else { int oc = o - 30; int g = oc / 3, j = oc - g * 3;
               out[178176 + g * 3072 + b * 3 + j] = r; }
      }
    }
  }
}

// ---------- glibc (fdlibm) acosf port (validated R10-R13) ----------
__device__ __forceinline__ float acosf_glibc(float x) {
  #pragma clang fp contract(off)
  const float one = 1.0f;
  const float pi = 3.1415925026e+00f;
  const float pio2_hi = 1.5707962513e+00f;
  const float pio2_lo = 7.5497894159e-08f;
  const float pS0 =  1.6666586697e-01f;
  const float pS1 = -4.2743422091e-02f;
  const float pS2 = -8.6563630030e-03f;
  const float qS1 = -7.0662963390e-01f;
  int hx = __float_as_int(x);
  int ix = hx & 0x7fffffff;
  if (ix >= 0x3f800000) {
    if (ix == 0x3f800000) return (hx > 0) ? 0.0f : (pi + 2.0f * pio2_lo);
    return (x - x) / (x - x);
  }
  if (ix < 0x3f000000) {
    if (ix <= 0x32800000) return pio2_hi + pio2_lo;
    float z = x * x;
    float p = z * (pS0 + z * (pS1 + z * pS2));
    float q = one + z * qS1;
    float r = p / q;
    float t1 = x * r;
    float t2 = pio2_lo - t1;
    float t3 = x - t2;
    return pio2_hi - t3;
  } else if (hx < 0) {
    float z = (one + x) * 0.5f;
    float p = z * (pS0 + z * (pS1 + z * pS2));
    float q = one + z * qS1;
    float s = sqrtf(z);
    float r = p / q;
    float w = r * s - pio2_lo;
    float u = s + w;
    return pi - 2.0f * u;
  } else {
    float z = (one - x) * 0.5f;
    float s = sqrtf(z);
    float df = __int_as_float(__float_as_int(s) & 0xfffff000);
    float c = (z - df * df) / (s + df);
    float p = z * (pS0 + z * (pS1 + z * pS2));
    float q = one + z * qS1;
    float r = p / q;
    float w = r * s + c;
    float u = df + w;
    return 2.0f * u;
  }
}

// ---------- f32 rot6d, numpy op-for-op (validated R10-R13) ----------
__device__ __forceinline__ void emit_aa32(const float p[6], float* __restrict__ pout) {
  #pragma clang fp contract(off)
  const float CLO = (float)(-1.0 + 1e-6);
  const float CHI = (float)(1.0 - 1e-6);
  float a1x = p[0], a2x = p[1];
  float a1y = p[2], a2y = p[3];
  float a1z = p[4], a2z = p[5];
  float n1 = sqrtf(((a1x * a1x) + (a1y * a1y)) + (a1z * a1z));
  float n1c = fmaxf(n1, 1e-12f);
  float b1x = a1x / n1c, b1y = a1y / n1c, b1z = a1z / n1c;
  float d12 = ((b1x * a2x) + (b1y * a2y)) + (b1z * a2z);
  float px = a2x - (d12 * b1x);
  float py = a2y - (d12 * b1y);
  float pz = a2z - (d12 * b1z);
  float n2 = sqrtf(((px * px) + (py * py)) + (pz * pz));
  float n2c = fmaxf(n2, 1e-12f);
  float b2x = px / n2c, b2y = py / n2c, b2z = pz / n2c;
  float b3x = (b1y * b2z) - (b1z * b2y);
  float b3y = (b1z * b2x) - (b1x * b2z);
  float b3z = (b1x * b2y) - (b1y * b2x);
  float tr = (b1x + b2y) + b3z;
  float cth = (tr - 1.0f) * 0.5f;
  cth = fminf(fmaxf(cth, CLO), CHI);
  float ang = acosf_glibc(cth);
  float sn = (float)sin((double)ang);
  float sc = ang / (2.0f * sn);
  pout[0] = (b2z - b3y) * sc;
  pout[1] = (b3x - b1z) * sc;
  pout[2] = (b1y - b2x) * sc;
}

// ---------- finish tails per stream + bias + rot6d (== R13 chain) ----------
__global__ __launch_bounds__(256) void chain_np(
    const float* __restrict__ partA, const float* __restrict__ partB,
    const float* __restrict__ partC,
    const float* __restrict__ fj_e1, const float* __restrict__ fj_md,
    const float* __restrict__ fj_e2, const float* __restrict__ ji_e1,
    const float* __restrict__ ji_md, const float* __restrict__ ji_e2,
    const float* __restrict__ reg_w, const float* __restrict__ reg_b,
    float* __restrict__ out) {
  #pragma clang fp contract(off)
  int t = blockIdx.x * 256 + threadIdx.x;
  if (t >= MROWS) return;
  int s = t >> 10, b = t & 1023;
  const float* fjs = (s == 0) ? fj_e1 : (s == 1) ? fj_md : fj_e2;
  const float* jis = (s == 0) ? ji_e1 : (s == 1) ? ji_md : ji_e2;
  float* pout = out + 30720 + s * (BATCH * 48) + b * 48;

  // xall[k] = x at d = 10744+k; k<71 from inputs, k=71..88 ancestor slots.
  float xall[89];
  #pragma unroll
  for (int k = 0; k < 68; ++k) xall[k] = fjs[(size_t)b * 10752 + 10684 + k];
  #pragma unroll
  for (int k = 0; k < 3; ++k) xall[68 + k] = jis[b * 63 + 60 + k];

  float p0[6], pa[6], pb[6], pc[6];
  float anc[18];

  auto do_joint = [&](int i, int na, float* pz) {
    #pragma unroll
    for (int k = 0; k < 18; ++k) xall[71 + k] = (k < na * 6) ? anc[k] : 0.f;
    #pragma unroll
    for (int oo = 0; oo < 6; ++oo) {
      const float* w = reg_w + (size_t)(i * 6 + oo) * DPAD;
      float total;
      if (s == 0) {
        // BLAS-B: continue live panel ascending FMA d 10752..10832, res+acc
        const float* pp = partA + ((size_t)b * NOUT + i * 6 + oo) * 2;
        float res = pp[0], acc = pp[1];
        #pragma unroll
        for (int k = 8; k < 89; ++k)
          acc = __builtin_fmaf(xall[k], w[10744 + k], acc);
        total = res + acc;
      } else if (s == 1) {
        // SSE3 npyv: blocks 672..676 desc subs; tillz d=10832 -> lane0; hsum
        const float* pp = partB + ((size_t)b * NOUT + i * 6 + oo) * 4;
        float v[4] = {pp[0], pp[1], pp[2], pp[3]};
        #pragma unroll
        for (int j = 0; j < 5; ++j) {
          int base = 8 + 16 * j;
          int wd = 10752 + 16 * j;
          #pragma unroll
          for (int l = 0; l < 4; ++l) { float q = xall[base + 12 + l] * w[wd + 12 + l]; v[l] = v[l] + q; }
          #pragma unroll
          for (int l = 0; l < 4; ++l) { float q = xall[base + 8 + l]  * w[wd + 8 + l];  v[l] = v[l] + q; }
          #pragma unroll
          for (int l = 0; l < 4; ++l) { float q = xall[base + 4 + l]  * w[wd + 4 + l];  v[l] = v[l] + q; }
          #pragma unroll
          for (int l = 0; l < 4; ++l) { float q = xall[base + l]      * w[wd + l];      v[l] = v[l] + q; }
        }
        { float q = xall[88] * w[10832]; v[0] = v[0] + q; }
        total = (v[0] + v[1]) + (v[2] + v[3]);
      } else {
        // AVX2 npyv: blocks 336,337 desc-FMA; 2 vstep + tillz lane0; hsum8
        const float* pp = partC + ((size_t)b * NOUT + i * 6 + oo) * 8;
        float v[8] = {pp[0], pp[1], pp[2], pp[3], pp[4], pp[5], pp[6], pp[7]};
        #pragma unroll
        for (int l = 0; l < 8; ++l) {
          float x = v[l];
          x = __builtin_fmaf(xall[32 + l], w[10776 + l], x);   // ab3
          x = __builtin_fmaf(xall[24 + l], w[10768 + l], x);
          x = __builtin_fmaf(xall[16 + l], w[10760 + l], x);
          x = __builtin_fmaf(xall[8 + l],  w[10752 + l], x);
          v[l] = x;
        }
        #pragma unroll
        for (int l = 0; l < 8; ++l) {
          float x = v[l];
          x = __builtin_fmaf(xall[64 + l], w[10808 + l], x);   // ab3
          x = __builtin_fmaf(xall[56 + l], w[10800 + l], x);
          x = __builtin_fmaf(xall[48 + l], w[10792 + l], x);
          x = __builtin_fmaf(xall[40 + l], w[10784 + l], x);
          v[l] = x;
        }
        #pragma unroll
        for (int l = 0; l < 8; ++l) v[l] = __builtin_fmaf(xall[72 + l], w[10816 + l], v[l]);
        #pragma unroll
        for (int l = 0; l < 8; ++l) v[l] = __builtin_fmaf(xall[80 + l], w[10824 + l], v[l]);
        v[0] = __builtin_fmaf(xall[88], w[10832], v[0]);
        total = ((v[0] + v[1]) + (v[2] + v[3])) + ((v[4] + v[5]) + (v[6] + v[7]));
      }
      pz[oo] = total + reg_b[i * 6 + oo];
    }
    emit_aa32(pz, pout + i * 3);
  };

  do_joint(0, 0, p0);
  for (int f = 1; f < 16; f += 3) {
    #pragma unroll
    for (int k = 0; k < 6; ++k) anc[k] = p0[k];
    do_joint(f, 1, pa);
    #pragma unroll
    for (int k = 0; k < 6; ++k) anc[6 + k] = pa[k];
    do_joint(f + 1, 2, pb);
    #pragma unroll
    for (int k = 0; k < 6; ++k) anc[12 + k] = pb[k];
    do_joint(f + 2, 3, pc);
  }
}

extern "C" void kernel_launch(void* const* d_in, const int* in_sizes, int n_in,
                              void* d_out, int out_size, void* d_ws, size_t ws_size,
                              hipStream_t stream) {
  (void)in_sizes; (void)n_in; (void)out_size; (void)ws_size;
  const float* feat_blur = (const float*)d_in[0];
  const float* fj_e1 = (const float*)d_in[1];
  const float* fj_md = (const float*)d_in[2];
  const float* fj_e2 = (const float*)d_in[3];
  const float* ji_e1 = (const float*)d_in[4];
  const float* ji_md = (const float*)d_in[5];
  const float* ji_e2 = (const float*)d_in[6];
  const float* shape_w = (const float*)d_in[7];
  const float* shape_b = (const float*)d_in[8];
  const float* cam_w = (const float*)d_in[9];
  const float* cam_b = (const float*)d_in[10];
  const float* reg_w = (const float*)d_in[11];
  const float* reg_b = (const float*)d_in[12];
  float* out = (float*)d_out;
  float* ws = (float*)d_ws;
  float* partA = ws;                       // e1 BLAS-B   [1024][96][2]
  float* partB = ws + 196608;              // md SSE3     [1024][96][4]
  float* partC = ws + 196608 + 393216;     // e2 AVX2     [1024][96][8]

  hipLaunchKernelGGL(fused_all, dim3(GEMM_BLOCKS + POOL_BLOCKS), dim3(256), 0, stream,
                     feat_blur, shape_w, shape_b, cam_w, cam_b,
                     fj_e1, fj_md, fj_e2, ji_e1, ji_md, ji_e2, reg_w,
                     partA, partB, partC, out);
  hipLaunchKernelGGL(chain_np, dim3((MROWS + 255) / 256), dim3(256), 0, stream,
                     partA, partB, partC, fj_e1, fj_md, fj_e2,
                     ji_e1, ji_md, ji_e2, reg_w, reg_b, out);
}